// Round 3
// baseline (105.378 us; speedup 1.0000x reference)
//
#include <hip/hip_runtime.h>
#include <hip/hip_bf16.h>

#define MTOK 16384
#define DDIM 2048
#define NEXP 8
#define RNK 16
#define NC 128          // E*R down-projection columns
#define NW 160          // padded GEMM1 N: 128 h + 8 logits + 24 zero pad
#define BM 32           // token rows per block
#define NT2 (DDIM / 64) // 32 K-steps of 64

typedef __attribute__((ext_vector_type(8))) short bf16x8;
typedef __attribute__((ext_vector_type(4))) short short4v;
typedef __attribute__((ext_vector_type(4))) float f32x4;

typedef __attribute__((address_space(1))) const void gv_t;
typedef __attribute__((address_space(3))) void lv_t;

__device__ __forceinline__ short f2b(float f) {
  unsigned u = __float_as_uint(f);
  u += 0x7fffu + ((u >> 16) & 1u);   // round-to-nearest-even
  return (short)(u >> 16);
}

// ---------------- K0: weight prep (fp32 -> bf16, transposed layouts) -------
// WdT pre-swizzled per 64-elem K-tile: linear position slot s holds logical
// slot s^(n&7), so linear global_load_lds + swizzled ds_read_b128 is
// bank-conflict-free (T2 via pre-swizzled source).
// Logical WdT[n][k]: n<128 -> down[n>>4][k][n&15]; 128..135 -> rw[n-128][k]; else 0
// UT[d][c]: up[c>>4][c&15][d]  (B-operand N x K for phase 2)
__global__ __launch_bounds__(256) void prep_k(const float* __restrict__ rw,
                                              const float* __restrict__ down,
                                              const float* __restrict__ up,
                                              short* __restrict__ WdT,
                                              short* __restrict__ UT) {
  int i = blockIdx.x * 256 + threadIdx.x;
  const int NWD = NW * DDIM;          // 327680
  const int NUT = DDIM * NC;          // 262144
  if (i < NWD) {
    int n = i / DDIM, k = i % DDIM;
    int s = (k >> 3) & 7;
    int src_k = (k & ~0x3F) | ((s ^ (n & 7)) << 3) | (k & 7);
    float v = 0.f;
    if (n < NC)             v = down[((n >> 4) * DDIM + src_k) * RNK + (n & 15)];
    else if (n < NC + NEXP) v = rw[(n - NC) * DDIM + src_k];
    WdT[i] = f2b(v);
  } else if (i < NWD + NUT) {
    int u = i - NWD;
    int d = u >> 7, c = u & 127;
    UT[u] = f2b(up[((c >> 4) * RNK + (c & 15)) * DDIM + d]);
  }
}

// ---------------- Fused: GEMM1 + routing + GEMM2 + residual ----------------
// 512 blocks x 256 thr, 2 blocks/CU. Each block owns 32 tokens end-to-end.
__global__ __launch_bounds__(256, 2) void fused_k(const float* __restrict__ X,
                                                  const short* __restrict__ WdT,
                                                  const short* __restrict__ UT,
                                                  float* __restrict__ Out) {
  __shared__ short Al[2][BM][72];      // 9216 B (+8 pad)
  __shared__ short Bl[2][160 * 64];    // 40960 B, linear for global_load_lds
  __shared__ short HwS[BM][136];       // 8704 B, scaled h (bf16)
  __shared__ float lg[BM][8];          // logits
  __shared__ float wv[BM][8];          // routing weights
  const int tid = threadIdx.x;
  const int lane = tid & 63;
  const int w = tid >> 6;
  const int gm0 = blockIdx.x * BM;
  const int wr = (w & 1) * 16;         // wave row base (16 rows)
  const int wc = (w >> 1) * 80;        // wave col base (5 frags of 16)
  const int lr = lane & 15;
  const int lk = (lane >> 4) * 8;

  // ---------------- phase 1: h/logits = X @ WdT^T --------------------------
  f32x4 acc[5];
#pragma unroll
  for (int n = 0; n < 5; ++n) acc[n] = (f32x4){0.f, 0.f, 0.f, 0.f};

  float4 aR[2];   // A staging: 32x64 fp32 = 256 thr * 2 * float4

  auto loadA = [&](int k0) {
#pragma unroll
    for (int i2 = 0; i2 < 2; ++i2) {
      int f = tid + 256 * i2;
      int row = f >> 4, c4 = f & 15;
      aR[i2] = *(const float4*)(X + (size_t)(gm0 + row) * DDIM + k0 + c4 * 4);
    }
  };
  auto issueB = [&](int buf, int k0) {
    // 160x64 bf16 = 1280 x 16B units; 4 waves x 5 calls x 64 lanes
#pragma unroll
    for (int j = 0; j < 5; ++j) {
      int u = (w * 5 + j) * 64 + lane;
      const short* g = WdT + (size_t)(u >> 3) * DDIM + k0 + (u & 7) * 8;
      short* l = &Bl[buf][(w * 5 + j) * 512];   // wave-uniform base
      __builtin_amdgcn_global_load_lds((gv_t*)g, (lv_t*)l, 16, 0, 0);
    }
  };
  auto writeA = [&](int buf) {
#pragma unroll
    for (int i2 = 0; i2 < 2; ++i2) {
      int f = tid + 256 * i2;
      int row = f >> 4, c4 = f & 15;
      short4v v;
      v.x = f2b(aR[i2].x); v.y = f2b(aR[i2].y);
      v.z = f2b(aR[i2].z); v.w = f2b(aR[i2].w);
      *(short4v*)&Al[buf][row][c4 * 4] = v;
    }
  };
  auto compute = [&](int buf) {
#pragma unroll
    for (int kk2 = 0; kk2 < 2; ++kk2) {
      const int kk = kk2 * 32;
      bf16x8 a = *(const bf16x8*)&Al[buf][wr + lr][kk + lk];
      bf16x8 b[5];
#pragma unroll
      for (int n = 0; n < 5; ++n) {
        int row = wc + n * 16 + lr;
        int sl = ((kk >> 3) + (lane >> 4)) ^ (row & 7);   // swizzled 16B slot
        b[n] = *(const bf16x8*)&Bl[buf][row * 64 + sl * 8];
      }
#pragma unroll
      for (int n = 0; n < 5; ++n)
        acc[n] = __builtin_amdgcn_mfma_f32_16x16x32_bf16(a, b[n], acc[n], 0, 0, 0);
    }
  };

  loadA(0);
  issueB(0, 0);
  writeA(0);
  __syncthreads();
  for (int t = 0; t < NT2; ++t) {
    const int cur = t & 1, nxt = cur ^ 1;
    if (t + 1 < NT2) {
      loadA((t + 1) * 64);
      issueB(nxt, (t + 1) * 64);
    }
    compute(cur);
    if (t + 1 < NT2) writeA(nxt);
    __syncthreads();
  }

  // ---------------- routing: top2 softmax on logits (cols 128-135) ---------
  // Waves 2,3 (wc=80) hold logits in frag n=3 (cols 128-143), lanes lr<8.
  if (wc == 80 && lr < 8) {
#pragma unroll
    for (int r = 0; r < 4; ++r)
      lg[wr + (lane >> 4) * 4 + r][lr] = acc[3][r];
  }
  __syncthreads();
  if (tid < BM) {
    float b0 = -1e30f, b1 = -1e30f;
    int i0 = 0, i1 = 0;
#pragma unroll
    for (int e = 0; e < 8; ++e) {
      float v = lg[tid][e];
      if (v > b0) { b1 = b0; i1 = i0; b0 = v; i0 = e; }   // lax.top_k tie-break
      else if (v > b1) { b1 = v; i1 = e; }
    }
    float ex = __expf(b1 - b0);
    float inv = 1.f / (1.f + ex);
#pragma unroll
    for (int e = 0; e < 8; ++e)
      wv[tid][e] = (e == i0) ? inv : ((e == i1) ? ex * inv : 0.f);
  }
  __syncthreads();

  // scale h by routing weight -> HwS (bf16). w0/w1: cols 0-79; w2/w3: 80-127.
  {
    const int cmax = (wc == 0) ? 5 : 3;
#pragma unroll
    for (int n = 0; n < 5; ++n) {
      if (n >= cmax) break;
      int col = wc + n * 16 + lr;
#pragma unroll
      for (int r = 0; r < 4; ++r) {
        int row = wr + (lane >> 4) * 4 + r;
        HwS[row][col] = f2b(acc[n][r] * wv[row][col >> 4]);
      }
    }
  }
  __syncthreads();

  // ---------------- phase 2: Out = X + HwS @ UT^T --------------------------
  // Each wave: all 32 rows x 512 cols [w*512, (w+1)*512).
  bf16x8 af[2][4];
#pragma unroll
  for (int m = 0; m < 2; ++m)
#pragma unroll
    for (int kc = 0; kc < 4; ++kc)
      af[m][kc] = *(const bf16x8*)&HwS[m * 16 + lr][kc * 32 + lk];

  const int ncol0 = w * 512;
  for (int nb = 0; nb < 8; ++nb) {
#pragma unroll
    for (int nf = 0; nf < 4; ++nf) {
      const int c0 = ncol0 + nb * 64 + nf * 16;
      bf16x8 bfr[4];
#pragma unroll
      for (int kc = 0; kc < 4; ++kc)
        bfr[kc] = *(const bf16x8*)(UT + (size_t)(c0 + lr) * NC + kc * 32 + lk);
      f32x4 a2[2];
#pragma unroll
      for (int m = 0; m < 2; ++m) a2[m] = (f32x4){0.f, 0.f, 0.f, 0.f};
#pragma unroll
      for (int m = 0; m < 2; ++m)
#pragma unroll
        for (int kc = 0; kc < 4; ++kc)
          a2[m] = __builtin_amdgcn_mfma_f32_16x16x32_bf16(af[m][kc], bfr[kc], a2[m], 0, 0, 0);
#pragma unroll
      for (int m = 0; m < 2; ++m)
#pragma unroll
        for (int r = 0; r < 4; ++r) {
          int row = gm0 + m * 16 + (lane >> 4) * 4 + r;
          size_t idx = (size_t)row * DDIM + c0 + lr;
          Out[idx] = X[idx] + a2[m][r];
        }
    }
  }
}

// ---------------------------------------------------------------------------
extern "C" void kernel_launch(void* const* d_in, const int* in_sizes, int n_in,
                              void* d_out, int out_size, void* d_ws, size_t ws_size,
                              hipStream_t stream) {
  const float* x    = (const float*)d_in[0];
  const float* rw   = (const float*)d_in[1];
  const float* down = (const float*)d_in[2];
  const float* up   = (const float*)d_in[3];
  float* out = (float*)d_out;

  char* ws = (char*)d_ws;
  short* WdT = (short*)ws;                 // 160*2048*2 = 655360 B
  short* UT  = (short*)(ws + 655360);      // 2048*128*2 = 524288 B

  prep_k<<<2304, 256, 0, stream>>>(rw, down, up, WdT, UT);
  fused_k<<<MTOK / BM, 256, 0, stream>>>(x, WdT, UT, out);   // 512 blocks
}